// Round 2
// 542.229 us; speedup vs baseline: 1.0096x; 1.0096x over previous
//
#include <hip/hip_runtime.h>

// Problem constants
#define B_ 8
#define L_ 128
#define D_ 768
#define JH 64                     // j's per block (j-split factor 2)
#define UN 4                      // dep-loop prefetch group size

typedef float v4f __attribute__((ext_vector_type(4)));

// ---------------------------------------------------------------------------
// Kernel A: partial aggregation.
//   P[s][b*L+i][d] = sum_{j in half s} adj[b,i,j] * (text[b,j,d] + dep[b,j,i,d])
// Block = (b, row-pair, j-half): 2 rows x 64 j's; 1024 blocks x 192 threads.
//  - 2 adjacent i rows -> 6 KB contiguous dep per j step (vs 3 KB before),
//    halves the number of interleaved DRAM walk-streams.
//  - explicit register double-buffer: next group's 8 NT loads are issued
//    before the current group's FMAs, guaranteeing >=8 KB/wave in flight
//    regardless of compiler pipelining across unroll boundaries.
//  - text (L2-resident, ~200cy) handled in a separate short loop so the dep
//    stream loop issues nothing but HBM loads; text L2 traffic also halves.
//  - adj staged as float2 pairs: 1 ds_read_b64 broadcast per j, not 2 b32.
// ---------------------------------------------------------------------------
__global__ __launch_bounds__(192) void agg_kernel(
    const float* __restrict__ text,       // [B][L][D]
    const float* __restrict__ adj,        // [B][L][L]
    const float* __restrict__ dep,        // [B][L][L][D]
    float* __restrict__ P) {              // [2][B*L][D] partials
  const int bx = blockIdx.x;              // 0..1023
  const int jh = bx & 1;
  const int p  = (bx >> 1) & 63;
  const int b  = bx >> 7;
  const int i0 = p * 2;
  const int t  = threadIdx.x;             // 0..191 (one float4 column each)
  const int j0 = jh * JH;

  __shared__ float a_s[JH][2];            // adj pairs, float2-readable
  if (t < 2 * JH) {
    const int r  = t >> 6;                // which of the 2 rows
    const int jj = t & 63;
    a_s[jj][r] = adj[((size_t)b * L_ + i0 + r) * L_ + j0 + jj];
  }
  __syncthreads();

  const v4f* dep4 = (const v4f*)(dep + (((size_t)b * L_ + j0) * L_ + i0) * D_);
  const size_t jstr = (size_t)L_ * D_ / 4;         // v4f stride per j step

  v4f acc0 = {0.f, 0.f, 0.f, 0.f};
  v4f acc1 = {0.f, 0.f, 0.f, 0.f};

  // ---- dep streaming loop: register double-buffered NT loads ----
  v4f c0[UN], c1[UN];
#pragma unroll
  for (int u = 0; u < UN; ++u) {
    c0[u] = __builtin_nontemporal_load(&dep4[(size_t)u * jstr + t]);
    c1[u] = __builtin_nontemporal_load(&dep4[(size_t)u * jstr + (D_ / 4) + t]);
  }
  for (int jb = 0; jb < JH; jb += UN) {
    v4f n0[UN], n1[UN];
    if (jb + UN < JH) {
#pragma unroll
      for (int u = 0; u < UN; ++u) {
        n0[u] = __builtin_nontemporal_load(&dep4[(size_t)(jb + UN + u) * jstr + t]);
        n1[u] = __builtin_nontemporal_load(&dep4[(size_t)(jb + UN + u) * jstr + (D_ / 4) + t]);
      }
    }
#pragma unroll
    for (int u = 0; u < UN; ++u) {
      const float2 av = *(const float2*)&a_s[jb + u][0];
      acc0 += av.x * c0[u];
      acc1 += av.y * c1[u];
    }
#pragma unroll
    for (int u = 0; u < UN; ++u) { c0[u] = n0[u]; c1[u] = n1[u]; }
  }

  // ---- text loop: L2-resident, short ----
  const v4f* text4 = (const v4f*)(text + ((size_t)b * L_ + j0) * D_);
#pragma unroll 8
  for (int j = 0; j < JH; ++j) {
    const float2 av = *(const float2*)&a_s[j][0];
    const v4f tx = text4[(size_t)j * (D_ / 4) + t];
    acc0 += av.x * tx;
    acc1 += av.y * tx;
  }

  float* Prow = P + ((size_t)jh * (B_ * L_) + (size_t)b * L_ + i0) * D_;
  ((v4f*)Prow)[t] = acc0;
  ((v4f*)Prow)[D_ / 4 + t] = acc1;
}

// ---------------------------------------------------------------------------
// Kernel B: out[m][n] = relu( sum_k (P0[m][k]+P1[m][k]) * W[k][n] + bias[n] )
// Same 32x64-tile structure as before; the only change is the A-loader sums
// the two j-half partials (2 loads instead of 1, folded at the LDS write).
// ---------------------------------------------------------------------------
#define TM 32
#define TN 64
#define TK 32
#define NKT (D_ / TK)                     // 24 K-tiles

__global__ __launch_bounds__(256) void gemm_bias_relu(
    const float* __restrict__ P,          // [2][M][K] partials (agg)
    const float* __restrict__ W,          // [K][N]
    const float* __restrict__ bias,       // [N]
    float* __restrict__ out) {            // [M][N]
  __shared__ float AsT[TK][TM + 2];       // transposed A tile
  __shared__ float Bs[TK][TN];

  const int tid = threadIdx.x;
  const int tx  = tid & 15;               // n-direction (16 x float4 = 64)
  const int ty  = tid >> 4;               // m-direction (16 x 2 rows = 32)
  const int m0  = blockIdx.y * TM;
  const int n0  = blockIdx.x * TN;

  // loader indices
  const int ar  = tid >> 3;               // 0..31  A row
  const int ac  = (tid & 7) * 4;          // float4 k-col within K-tile
  const int br  = tid >> 4;               // 0..15  W row in K-tile (+16 second)
  const int bc  = (tid & 15) * 4;         // float4 n-col within N-tile

  const float* A0row = P + (size_t)(m0 + ar) * D_ + ac;
  const float* A1row = A0row + (size_t)(B_ * L_) * D_;
  const float* Wrow0 = W + (size_t)br * D_ + n0 + bc;
  const float* Wrow1 = W + (size_t)(br + 16) * D_ + n0 + bc;

  float acc[2][4] = {};

  // prefetch tile 0
  v4f a0_reg = *(const v4f*)A0row;
  v4f a1_reg = *(const v4f*)A1row;
  v4f b_reg0 = *(const v4f*)Wrow0;
  v4f b_reg1 = *(const v4f*)Wrow1;

  for (int t = 0; t < NKT; ++t) {
    __syncthreads();                      // previous tile's reads done
    const v4f asum = a0_reg + a1_reg;
    AsT[ac + 0][ar] = asum.x;
    AsT[ac + 1][ar] = asum.y;
    AsT[ac + 2][ar] = asum.z;
    AsT[ac + 3][ar] = asum.w;
    *(v4f*)&Bs[br][bc]      = b_reg0;
    *(v4f*)&Bs[br + 16][bc] = b_reg1;
    __syncthreads();

    // issue next tile's loads now; they complete under the compute below
    if (t + 1 < NKT) {
      a0_reg = *(const v4f*)(A0row + (t + 1) * TK);
      a1_reg = *(const v4f*)(A1row + (t + 1) * TK);
      b_reg0 = *(const v4f*)(Wrow0 + (size_t)(t + 1) * TK * D_);
      b_reg1 = *(const v4f*)(Wrow1 + (size_t)(t + 1) * TK * D_);
    }

#pragma unroll
    for (int kk = 0; kk < TK; ++kk) {
      const float2 av = *(const float2*)&AsT[kk][ty * 2];
      const v4f    bv = *(const v4f*)&Bs[kk][tx * 4];
#pragma unroll
      for (int pn = 0; pn < 4; ++pn) {
        acc[0][pn] += av.x * bv[pn];
        acc[1][pn] += av.y * bv[pn];
      }
    }
  }

  const v4f bvec = *(const v4f*)&bias[n0 + tx * 4];
#pragma unroll
  for (int pm = 0; pm < 2; ++pm) {
    v4f o;
#pragma unroll
    for (int pn = 0; pn < 4; ++pn) o[pn] = fmaxf(acc[pm][pn] + bvec[pn], 0.f);
    *(v4f*)&out[(size_t)(m0 + ty * 2 + pm) * D_ + n0 + tx * 4] = o;
  }
}

extern "C" void kernel_launch(void* const* d_in, const int* in_sizes, int n_in,
                              void* d_out, int out_size, void* d_ws, size_t ws_size,
                              hipStream_t stream) {
  const float* text   = (const float*)d_in[0];  // [B][L][D]
  const float* adj    = (const float*)d_in[1];  // [B][L][L]
  const float* dep    = (const float*)d_in[2];  // [B][L][L][D]
  const float* weight = (const float*)d_in[3];  // [D][D]
  const float* bias   = (const float*)d_in[4];  // [D]
  float* out = (float*)d_out;                   // [B][L][D]
  float* P   = (float*)d_ws;                    // [2][B*L][D] = 6 MB scratch

  agg_kernel<<<B_ * L_ * 2 / 2, 192, 0, stream>>>(text, adj, dep, P);  // 1024 blocks

  dim3 grid(D_ / TN, (B_ * L_) / TM);           // 12 x 32 = 384 blocks
  gemm_bias_relu<<<grid, 256, 0, stream>>>(P, weight, bias, out);
}